// Round 4
// baseline (298.363 us; speedup 1.0000x reference)
//
#include <hip/hip_runtime.h>
#include <hip/hip_bf16.h>

// StyleGAN2-style modulated conv. B=16, C=128 (o==i), H=W=128, K=3.
// out[b,o,y,x] = sum_{i,ky,kx} wmod[b,o,i,ky,kx] * xpad[b,i,y+ky-1,x+kx-1]
// wmod = w * (1/sqrt(1152)/wmax[o]) * sn[b,i] * coe[b,o]
//
// R2: bf16 MFMA implicit GEMM, weights pre-swizzled to A-frag-linear bf16.
// R4: LDS double-buffer + staging weave (spilled at 256thr/2blk).
// R5: 512-thr / 8-wave, acc[2][8], weave -> 127us. LDS-read pipe (576 b128
//     /chunk/CU = 6.9Kcy) exceeded MFMA pipe (5.6Kcy); B-reads on critical path.
// R6 (this round): wave tile 2x8 -> 4x4 (64o x 64px): B-frag reads/tap
//     halve (8->4, LDS pipe 3.5Kcy < MFMA 5.6Kcy); A-frags dup'd across
//     waves sharing ohalf (L1 broadcast). Explicit B double-buffer:
//     tap k+1's ds_reads issue before tap k's MFMAs (hides LDS latency).

#define BATCH 16
#define CH    128
#define HW    128
#define WPITCH 1152   // CH*9

// ws layout (floats region only used by fallback path):
//   floats: [0,128) wmax | [128,2176) sn | [2176,4224) Afac | [4224,+147456) w_t
//   bytes 606720...: wfrag bf16, [b][kk][ci(4)][mo(8)][lane(64)][j(8)]
#define WS_WMAX 0
#define WS_SN   128
#define WS_AFAC 2176
#define WS_WT   4224
#define WFRAG_BYTE_OFF 606720
#define WFRAG_BYTES    4718592
#define WS_NEEDED      (WFRAG_BYTE_OFF + WFRAG_BYTES)

typedef short  s8v  __attribute__((ext_vector_type(8)));
typedef float  f4v  __attribute__((ext_vector_type(4)));
typedef float  f2v  __attribute__((ext_vector_type(2)));

__device__ inline unsigned short f2bf(float f) {
    union { float f; unsigned int u; } v; v.f = f;
    unsigned int r = v.u + 0x7FFFu + ((v.u >> 16) & 1u);   // RNE
    return (unsigned short)(r >> 16);
}

// ---------------------------------------------------------------- kprep: fused norms + demod + frag swizzle
// grid = 128 blocks: blockIdx.x = b*8 + mo.
__global__ __launch_bounds__(256) void kprep(const float* __restrict__ style,
                                             const float* __restrict__ weight,
                                             unsigned short* __restrict__ wfrag) {
    const int b  = blockIdx.x >> 3;
    const int mo = blockIdx.x & 7;
    const int t  = threadIdx.x;

    __shared__ float wrow[16 * 1153];   // pitch 1153 -> conflict-free
    __shared__ float snl[128];
    __shared__ float afl[16];
    __shared__ float red[4];

    // --- 1. style norm
    float sv = (t < 128) ? style[b * CH + t] : 0.f;
    float m = fabsf(sv);
    #pragma unroll
    for (int off = 32; off > 0; off >>= 1)
        m = fmaxf(m, __shfl_down(m, off, 64));
    if ((t & 63) == 0) red[t >> 6] = m;

    // --- 2. weight rows -> LDS (coalesced)
    for (int idx = t; idx < 16 * 1152; idx += 256) {
        int r = idx / 1152;
        int c = idx - r * 1152;
        wrow[r * 1153 + c] = weight[(size_t)(mo * 16 + r) * WPITCH + c];
    }
    __syncthreads();
    float smax = fmaxf(fmaxf(red[0], red[1]), fmaxf(red[2], red[3]));
    if (t < 128) snl[t] = sv / smax;
    __syncthreads();

    // --- 3. per-o stats: t = o16*16 + s
    const int o16 = t >> 4;
    const int s   = t & 15;
    float mx = 0.f, ss = 0.f;
    for (int c = s; c < 1152; c += 16) {
        float v = wrow[o16 * 1153 + c];
        mx = fmaxf(mx, fabsf(v));
        float u = v * snl[c / 9];
        ss += u * u;
    }
    #pragma unroll
    for (int off = 8; off > 0; off >>= 1) {
        mx = fmaxf(mx, __shfl_down(mx, off, 16));
        ss += __shfl_down(ss, off, 16);
    }
    if (s == 0) {
        float scale = 1.0f / (sqrtf(1152.0f) * mx);
        afl[o16] = scale * rsqrtf(scale * scale * ss + 1e-8f);
    }
    __syncthreads();

    // --- 4. frags: fid = [kk(9)][ci(4)][lane(64)] = 2304 uint4
    for (int fid = t; fid < 2304; fid += 256) {
        const int lane = fid & 63;
        int f2 = fid >> 6;
        const int ci = f2 & 3;
        const int kk = f2 >> 2;
        const int ro = lane & 15;
        const int i0 = ci * 32 + (lane >> 4) * 8;
        const float af = afl[ro];
        union { unsigned short u[8]; uint4 v; } pk;
        #pragma unroll
        for (int j = 0; j < 8; ++j) {
            int i = i0 + j;
            float v = wrow[ro * 1153 + i * 9 + kk] * af * snl[i];
            pk.u[j] = f2bf(v);
        }
        *(uint4*)(wfrag + ((size_t)(((b * 9 + kk) * 4 + ci) * 8 + mo) * 64 + lane) * 8) = pk.v;
    }
}

// ---------------------------------------------------------------- k4: MFMA conv, 8-wave double-buffered
// Block: 512 thr = 8 waves; tile 128 o x 256 px (rows h0, h0+1).
// Wave wid: ohalf = wid&1 (64 o), colhalf = (wid>>1)&1 (64 px), rsel = wid>>2.
// acc[4][4] = 64 AGPR. 4 B-frag reads / 16 MFMA per tap (B reuse = 4).
// LDS x-tile: [r(4)][c(130)][32ch] bf16, XOR swizzle qs = q ^ ((c>>1)&3).
// Double-buffered; staging of chunk ci+1 woven into taps of ci.
#define XBUF 16640   // shorts per buffer: 4*130*32

__device__ inline int xoff(int r, int c, int qs) { return (r * 130 + c) * 32 + qs * 8; }

__device__ inline const s8v* afrag_ptr(const unsigned short* wfrag, int b, int kk,
                                       int ci, int mo, int lane) {
    return (const s8v*)(wfrag + ((size_t)(((b * 9 + kk) * 4 + ci) * 8 + mo) * 64 + lane) * 8);
}

__global__ __launch_bounds__(512, 1) void k4_mfma(const float* __restrict__ x,
                                                  const unsigned short* __restrict__ wfrag,
                                                  float* __restrict__ out) {
    // bijective XCD swizzle (1024 % 8 == 0)
    const int wg  = blockIdx.x;
    const int swz = (wg & 7) * 128 + (wg >> 3);
    const int b   = swz >> 6;
    const int h0  = (swz & 63) * 2;

    const int t    = threadIdx.x;
    const int lane = t & 63;
    const int wid  = t >> 6;
    const int ohalf   = wid & 1;          // 64-o half
    const int colhalf = (wid >> 1) & 1;   // 64-px col half
    const int rsel    = wid >> 2;         // output row
    const int ln15  = lane & 15;
    const int quad  = lane >> 4;

    __shared__ unsigned short xls[2 * XBUF];

    // zero pad cols c=0 and c=129 in BOTH buffers once
    if (t < 64) {
        const int zb = (t >> 5) & 1;
        const int zr = (t >> 3) & 3;
        const int zc = ((t >> 2) & 1) ? 129 : 0;
        const int zq = t & 3;
        *(s8v*)&xls[zb * XBUF + xoff(zr, zc, zq)] = (s8v){0, 0, 0, 0, 0, 0, 0, 0};
    }

    f4v acc[4][4];
    #pragma unroll
    for (int mt = 0; mt < 4; ++mt)
        #pragma unroll
        for (int nt = 0; nt < 4; ++nt)
            acc[mt][nt] = (f4v){0.f, 0.f, 0.f, 0.f};

    // staging geometry (independent of compute decomposition):
    // wave stages row r = wid&3, channel-half hs = wid>>2; lane owns col pair.
    const int  cp     = lane;
    const int  sr     = wid & 3;
    const int  hs     = wid >> 2;
    const int  it0    = hs * 2;
    const int  it1    = hs * 2 + 1;
    const int  srow   = h0 - 1 + sr;
    const bool svalid = (unsigned)srow < 128u;
    const int  srcl   = svalid ? srow : 0;

    // --- prologue: stage chunk 0 into buf0
    #pragma unroll
    for (int k = 0; k < 2; ++k) {
        const int it = it0 + k;
        const float* xp = x + (((size_t)(b * CH + it * 8)) * HW + srcl) * HW + 2 * cp;
        union { unsigned short u[16]; s8v v[2]; } pk;
        #pragma unroll
        for (int j = 0; j < 8; ++j) {
            f2v d = *(const f2v*)(xp + (size_t)j * HW * HW);
            pk.u[j]     = f2bf(svalid ? d.x : 0.f);
            pk.u[8 + j] = f2bf(svalid ? d.y : 0.f);
        }
        *(s8v*)&xls[xoff(sr, 2 * cp + 1, it ^ (cp & 3))]       = pk.v[0];
        *(s8v*)&xls[xoff(sr, 2 * cp + 2, it ^ ((cp + 1) & 3))] = pk.v[1];
    }
    __syncthreads();

#define ISSUE(IT) do { \
    const float* xp_ = x + (((size_t)(b * CH + ibn + (IT) * 8)) * HW + srcl) * HW + 2 * cp; \
    _Pragma("unroll") \
    for (int j = 0; j < 8; ++j) pf[j] = *(const f2v*)(xp_ + (size_t)j * HW * HW); \
} while (0)

#define COMMIT(IT) do { \
    union { unsigned short u[16]; s8v v[2]; } pk_; \
    _Pragma("unroll") \
    for (int j = 0; j < 8; ++j) { \
        pk_.u[j]     = f2bf(svalid ? pf[j].x : 0.f); \
        pk_.u[8 + j] = f2bf(svalid ? pf[j].y : 0.f); } \
    *(s8v*)&bufn[xoff(sr, 2 * cp + 1, (IT) ^ (cp & 3))]       = pk_.v[0]; \
    *(s8v*)&bufn[xoff(sr, 2 * cp + 2, (IT) ^ ((cp + 1) & 3))] = pk_.v[1]; \
} while (0)

// load 4 B-frags for tap (KY,KX) of current buffer into DST
#define LOADB(DST, KY, KX) do { \
    const int r_ = rsel + (KY); \
    _Pragma("unroll") \
    for (int nt = 0; nt < 4; ++nt) { \
        const int c_ = colhalf * 64 + nt * 16 + ln15 + (KX); \
        (DST)[nt] = *(const s8v*)&bufc[xoff(r_, c_, quad ^ ((c_ >> 1) & 3))]; \
    } \
} while (0)

    // A-frag prefetch chain (one tap ahead)
    s8v aN[4];
    #pragma unroll
    for (int mt = 0; mt < 4; ++mt)
        aN[mt] = *afrag_ptr(wfrag, b, 0, 0, ohalf * 4 + mt, lane);

    #pragma unroll 1
    for (int ci = 0; ci < 4; ++ci) {
        unsigned short* bufc = xls + (ci & 1) * XBUF;
        unsigned short* bufn = xls + ((ci & 1) ^ 1) * XBUF;
        const int ibn = (ci + 1) * 32;
        f2v pf[8];

        // B double-buffer: preload tap 0
        s8v bfC[4], bfN[4];
        LOADB(bfC, 0, 0);

        #pragma unroll
        for (int kk = 0; kk < 9; ++kk) {
            // B-frags for NEXT tap issue before this tap's MFMAs
            if (kk < 8) {
                const int nky = (kk + 1) / 3;
                const int nkx = (kk + 1) - nky * 3;
                LOADB(bfN, nky, nkx);
            }
            s8v aC[4];
            #pragma unroll
            for (int mt = 0; mt < 4; ++mt) aC[mt] = aN[mt];
            {   // prefetch next tap's A-frags (or next chunk's tap 0)
                const int pci = (kk < 8) ? ci : ci + 1;
                const int pkk = (kk < 8) ? kk + 1 : 0;
                if (pci < 4) {
                    #pragma unroll
                    for (int mt = 0; mt < 4; ++mt)
                        aN[mt] = *afrag_ptr(wfrag, b, pkk, pci, ohalf * 4 + mt, lane);
                }
            }
            // staging weave: 2 issue/commit pairs per wave per chunk
            if (ci < 3) {
                if      (kk == 0) { ISSUE(it0); }
                else if (kk == 4) { COMMIT(it0); ISSUE(it1); }
                else if (kk == 8) { COMMIT(it1); }
            }
            #pragma unroll
            for (int mt = 0; mt < 4; ++mt)
                #pragma unroll
                for (int nt = 0; nt < 4; ++nt)
                    acc[mt][nt] = __builtin_amdgcn_mfma_f32_16x16x32_bf16(
                        aC[mt], bfC[nt], acc[mt][nt], 0, 0, 0);
            #pragma unroll
            for (int nt = 0; nt < 4; ++nt) bfC[nt] = bfN[nt];
        }
        __syncthreads();   // taps of ci done everywhere; buffer swap safe
    }
#undef ISSUE
#undef COMMIT
#undef LOADB

    // --- epilogue: C/D layout col(n=px)=lane&15, row(m=o)=quad*4+reg
    const int orow = h0 + rsel;
    #pragma unroll
    for (int mt = 0; mt < 4; ++mt) {
        int o = ohalf * 64 + mt * 16 + quad * 4;
        #pragma unroll
        for (int nt = 0; nt < 4; ++nt) {
            int xcol = colhalf * 64 + nt * 16 + ln15;
            float* op = out + (((size_t)(b * CH + o)) * HW + orow) * HW + xcol;
            #pragma unroll
            for (int reg = 0; reg < 4; ++reg)
                op[(size_t)reg * HW * HW] = acc[mt][nt][reg];
        }
    }
}

// ---------------------------------------------------------------- fallback path kernels (ws too small)
__global__ __launch_bounds__(256) void k0_transpose(const float* __restrict__ w,
                                                    float* __restrict__ ws) {
    int idx = blockIdx.x * 256 + threadIdx.x;
    if (idx < CH * WPITCH) {
        int kt = idx >> 7;
        int o  = idx & 127;
        ws[WS_WT + idx] = w[(size_t)o * WPITCH + kt];
    }
}

__global__ __launch_bounds__(256) void k1_norms(const float* __restrict__ style,
                                                const float* __restrict__ weight,
                                                float* __restrict__ ws) {
    __shared__ float red[4];
    const int bid = blockIdx.x;
    const int t = threadIdx.x;
    if (bid < 128) {
        const int o = bid;
        float m = 0.f;
        for (int idx = t; idx < WPITCH; idx += 256)
            m = fmaxf(m, fabsf(weight[(size_t)o * WPITCH + idx]));
        #pragma unroll
        for (int off = 32; off > 0; off >>= 1)
            m = fmaxf(m, __shfl_down(m, off, 64));
        if ((t & 63) == 0) red[t >> 6] = m;
        __syncthreads();
        if (t == 0)
            ws[WS_WMAX + o] = fmaxf(fmaxf(red[0], red[1]), fmaxf(red[2], red[3]));
    } else {
        const int b = bid - 128;
        float v = (t < CH) ? style[b * CH + t] : 0.f;
        float m = fabsf(v);
        #pragma unroll
        for (int off = 32; off > 0; off >>= 1)
            m = fmaxf(m, __shfl_down(m, off, 64));
        if ((t & 63) == 0) red[t >> 6] = m;
        __syncthreads();
        float smax = fmaxf(fmaxf(red[0], red[1]), fmaxf(red[2], red[3]));
        if (t < CH) ws[WS_SN + b * CH + t] = v / smax;
    }
}

__global__ __launch_bounds__(256) void k2_coe(const float* __restrict__ weight,
                                              float* __restrict__ ws) {
    const int o = blockIdx.x;
    const int b = blockIdx.y;
    const int t = threadIdx.x;
    const float* sn = ws + WS_SN + b * CH;
    float s = 0.f;
    for (int idx = t; idx < WPITCH; idx += 256) {
        int i = idx / 9;
        float v = weight[(size_t)o * WPITCH + idx] * sn[i];
        s += v * v;
    }
    #pragma unroll
    for (int off = 32; off > 0; off >>= 1) s += __shfl_down(s, off, 64);
    __shared__ float red[4];
    if ((t & 63) == 0) red[t >> 6] = s;
    __syncthreads();
    if (t == 0) {
        float S = red[0] + red[1] + red[2] + red[3];
        float wm = ws[WS_WMAX + o];
        float scale = 1.0f / (sqrtf(1152.0f) * wm);
        float coe = rsqrtf(scale * scale * S + 1e-8f);
        ws[WS_AFAC + b * CH + o] = scale * coe;
    }
}

#define TI    8
#define XPITCH 132
__global__ __launch_bounds__(256) void k3_conv(const float* __restrict__ x,
                                               const float* __restrict__ ws,
                                               float* __restrict__ out) {
    const int h = blockIdx.x;
    const int b = blockIdx.y;
    const int t = threadIdx.x;
    const int og = t >> 4;
    const int pg = t & 15;

    __shared__ float x_lds[TI * 3 * XPITCH];
    __shared__ float w_lds[TI * 9 * 128];
    __shared__ float Af_l[128];
    __shared__ float sn_l[128];

    if (t < 128) {
        Af_l[t] = ws[WS_AFAC + b * CH + t];
        sn_l[t] = ws[WS_SN + b * CH + t];
    }
    float acc[8][8];
    #pragma unroll
    for (int j = 0; j < 8; ++j)
        #pragma unroll
        for (int p = 0; p < 8; ++p) acc[j][p] = 0.f;

    const float4* wt4 = (const float4*)(ws + WS_WT);
    float4* w_lds4 = (float4*)w_lds;
    const float4* Af4 = (const float4*)Af_l;

    #pragma unroll 1
    for (int ci = 0; ci < CH / TI; ++ci) {
        const int ib = ci * TI;
        __syncthreads();
        for (int idx = t; idx < TI * 3 * 130; idx += 256) {
            int ti  = idx / 390;
            int rem = idx - ti * 390;
            int r   = rem / 130;
            int c   = rem - r * 130;
            int row = h + r - 1;
            int col = c - 1;
            float v = 0.f;
            if ((unsigned)row < 128u && (unsigned)col < 128u)
                v = x[(((size_t)b * CH + ib + ti) * HW + row) * HW + col];
            x_lds[(ti * 3 + r) * XPITCH + c] = v;
        }
        for (int idx = t; idx < TI * 9 * 32; idx += 256) {
            int kt = idx >> 5;
            int o4 = idx & 31;
            int ti = kt / 9;
            float4 wv = wt4[(size_t)ib * 9 * 32 + idx];
            float4 af = Af4[o4];
            float  s  = sn_l[ib + ti];
            float4 rr;
            rr.x = wv.x * af.x * s; rr.y = wv.y * af.y * s;
            rr.z = wv.z * af.z * s; rr.w = wv.w * af.w * s;
            w_lds4[idx] = rr;
        }
        __syncthreads();
        #pragma unroll 1
        for (int ti = 0; ti < TI; ++ti) {
            float xv[3][12];
            #pragma unroll
            for (int ky = 0; ky < 3; ++ky)
                #pragma unroll
                for (int q = 0; q < 3; ++q) {
                    float4 v = *(const float4*)&x_lds[(ti * 3 + ky) * XPITCH + pg * 8 + q * 4];
                    xv[ky][q*4+0] = v.x; xv[ky][q*4+1] = v.y;
                    xv[ky][q*4+2] = v.z; xv[ky][q*4+3] = v.w;
                }
            #pragma unroll
            for (int kk = 0; kk < 9; ++kk) {
                const int ky = kk / 3;
                const int kx = kk % 3;
                float wv[8];
                #pragma unroll
                for (int q = 0; q < 2; ++q) {
                    float4 v = *(const float4*)&w_lds[(ti * 9 + kk) * 128 + og * 8 + q * 4];
                    wv[q*4+0] = v.x; wv[q*4+1] = v.y; wv[q*4+2] = v.z; wv[q*4+3] = v.w;
                }
                #pragma unroll
                for (int j = 0; j < 8; ++j)
                    #pragma unroll
                    for (int p = 0; p < 8; ++p)
                        acc[j][p] = fmaf(wv[j], xv[ky][p + kx], acc[j][p]);
            }
        }
    }
    const size_t obase = ((size_t)b * CH) * (HW * HW) + (size_t)h * HW;
    #pragma unroll
    for (int j = 0; j < 8; ++j) {
        int o = og * 8 + j;
        float4 v0 = {acc[j][0], acc[j][1], acc[j][2], acc[j][3]};
        float4 v1 = {acc[j][4], acc[j][5], acc[j][6], acc[j][7]};
        *(float4*)&out[obase + (size_t)o * (HW * HW) + pg * 8]     = v0;
        *(float4*)&out[obase + (size_t)o * (HW * HW) + pg * 8 + 4] = v1;
    }
}

// ---------------------------------------------------------------- launch
extern "C" void kernel_launch(void* const* d_in, const int* in_sizes, int n_in,
                              void* d_out, int out_size, void* d_ws, size_t ws_size,
                              hipStream_t stream) {
    const float* x      = (const float*)d_in[0];
    const float* style  = (const float*)d_in[1];
    const float* weight = (const float*)d_in[2];
    float* out = (float*)d_out;
    float* ws  = (float*)d_ws;

    if (ws_size >= (size_t)WS_NEEDED) {
        unsigned short* wfrag = (unsigned short*)((char*)d_ws + WFRAG_BYTE_OFF);
        kprep<<<128, 256, 0, stream>>>(style, weight, wfrag);
        k4_mfma<<<1024, 512, 0, stream>>>(x, wfrag, out);
    } else {
        k0_transpose<<<(CH * WPITCH + 255) / 256, 256, 0, stream>>>(weight, ws);
        k1_norms<<<144, 256, 0, stream>>>(style, weight, ws);
        k2_coe<<<dim3(CH, BATCH), 256, 0, stream>>>(weight, ws);
        k3_conv<<<dim3(HW, BATCH), 256, 0, stream>>>(x, ws, out);
    }
}